// Round 12
// baseline (419.241 us; speedup 1.0000x reference)
//
#include <hip/hip_runtime.h>
#include <stdint.h>

// B=16, S=2048, D=128 attention, per-query scale folded into Q (with log2e),
// online softmax in exp2 domain, exact JAX partitionable-threefry dropout
// (key 42, p=0.1), @V.
// Round 12: 512-thread blocks (VGPR-safe; 1024-thr blocks always cap/spill),
// TQ=64 -> grid 512 = 2 blocks/CU = 16 waves/CU = 4 waves/SIMD.
// Waves = 2 q-groups(32 rows, fat QK) x 4 key-phases(16 keys).  PV is
// D-split (r11): each wave accumulates a 32-dim D-quarter over all 64 keys
// from the block-wide P tile -> accO only 16 VGPRs.  Block-common running
// max via per-iter LDS exchange.  K dbuf, V^T/P single, LDS 63.5 KB,
// 3 barriers/iter; epilogue = l-sum over phases + disjoint O stores.

#define B_ 16
#define S_ 2048
#define D_ 128
#define TQ 64
#define TK 64
#define NT (S_ / TK)
#define KSTR 136  // f16 stride, K rows (128 D + 8)
#define VSTR 72   // f16 stride, V^T rows (64 keys + 8)
#define PSTR 72   // f16 stride, P rows (64 keys + 8)

typedef float f32x4 __attribute__((ext_vector_type(4)));
typedef _Float16 f16x8 __attribute__((ext_vector_type(8)));
typedef _Float16 f16x2 __attribute__((ext_vector_type(2)));

union F32R16 { float4 q[4]; float f[16]; };

// DPP row_ror reductions over 16-lane row groups.
#define DPP_ROR(x, ctrl) \
  __int_as_float(__builtin_amdgcn_update_dpp(0, __float_as_int(x), (ctrl), 0xf, 0xf, true))
__device__ __forceinline__ float row16_max(float x) {
  x = fmaxf(x, DPP_ROR(x, 0x128));
  x = fmaxf(x, DPP_ROR(x, 0x124));
  x = fmaxf(x, DPP_ROR(x, 0x122));
  x = fmaxf(x, DPP_ROR(x, 0x121));
  return x;
}
__device__ __forceinline__ float row16_sum(float x) {
  x += DPP_ROR(x, 0x128);
  x += DPP_ROR(x, 0x124);
  x += DPP_ROR(x, 0x122);
  x += DPP_ROR(x, 0x121);
  return x;
}

// threefry2x32, 20 rounds, key = (0, 42)  [jax.random.key(42)]
__device__ __forceinline__ uint2 threefry2x32_0_42(uint32_t x0, uint32_t x1) {
  const uint32_t k0 = 0u, k1 = 42u;
  const uint32_t k2 = 0x1BD11BDAu ^ k0 ^ k1;
  x0 += k0; x1 += k1;
#define TFR(r) { x0 += x1; x1 = __builtin_rotateleft32(x1, r); x1 ^= x0; }
  TFR(13) TFR(15) TFR(26) TFR(6)
  x0 += k1; x1 += k2 + 1u;
  TFR(17) TFR(29) TFR(16) TFR(24)
  x0 += k2; x1 += k0 + 2u;
  TFR(13) TFR(15) TFR(26) TFR(6)
  x0 += k0; x1 += k1 + 3u;
  TFR(17) TFR(29) TFR(16) TFR(24)
  x0 += k1; x1 += k2 + 4u;
  TFR(13) TFR(15) TFR(26) TFR(6)
  x0 += k2; x1 += k0 + 5u;
#undef TFR
  return make_uint2(x0, x1);
}

// HW-verified (round 2): partitionable path, counter (0, j), xor-fold.
__device__ __forceinline__ uint32_t jax_bits(uint32_t j) {
  const uint2 tf = threefry2x32_0_42(0u, j);
  return tf.x ^ tf.y;
}

__global__ __launch_bounds__(512, 2)
void attn_mfma_kernel(const float* __restrict__ Q, const float* __restrict__ K,
                      const float* __restrict__ V, const float* __restrict__ ISF,
                      const float* __restrict__ DP, float* __restrict__ OUT) {
  extern __shared__ __align__(16) char smem[];
  _Float16* const sK0 = (_Float16*)smem;                // 64x136 f16 = 17408 B
  _Float16* const sK1 = (_Float16*)(smem + 17408);
  _Float16* const sVT = (_Float16*)(smem + 34816);      // 128x72 f16 = 18432 B
  _Float16* const sP  = (_Float16*)(smem + 53248);      // 64x72 f16  =  9216 B
  float*    const sMx = (float*)(smem + 62464);         // 4 phases x 64 rows

  const int t    = threadIdx.x;
  const int lane = t & 63;
  const int l15  = lane & 15;
  const int quad = lane >> 4;
  const int w    = t >> 6;       // 0..7
  const int qg   = w & 1;        // q-group: 32 rows
  const int kph  = w >> 1;       // key phase (16 QK keys) == D-quarter (PV)
  const int b    = blockIdx.y;
  const int qb   = blockIdx.x * TQ + qg * 32;

  const float kp = 1.0f - DP[0];
  const uint32_t TH9 = (__float_as_uint(1.0f + kp) & 0x7FFFFFu) << 9;

  float m_[2][4], l_[2][4];
  uint32_t jq[2][4];
  #pragma unroll
  for (int sub = 0; sub < 2; ++sub)
    #pragma unroll
    for (int r = 0; r < 4; ++r) {
      m_[sub][r] = -INFINITY;
      l_[sub][r] = 0.0f;
      jq[sub][r] = ((uint32_t)b << 22)
                 + (uint32_t)(qb + sub * 16 + quad * 4 + r) * (uint32_t)S_;
    }

  // ---- Q fragments (2 subtiles), f16, 1/isf and log2(e) folded in ----
  f16x8 qf[2][4];
  #pragma unroll
  for (int sub = 0; sub < 2; ++sub) {
    const int qrow = qb + sub * 16 + l15;
    const float qs = 1.4426950408889634f / ISF[b * S_ + qrow];
    const float* qp = Q + ((size_t)(b * S_ + qrow)) * D_;
    #pragma unroll
    for (int c = 0; c < 4; ++c) {
      const float4 a  = *(const float4*)(qp + c * 32 + quad * 8);
      const float4 d2 = *(const float4*)(qp + c * 32 + quad * 8 + 4);
      const float xs[8] = {a.x, a.y, a.z, a.w, d2.x, d2.y, d2.z, d2.w};
      f16x8 h;
      #pragma unroll
      for (int j = 0; j < 8; ++j) h[j] = (_Float16)(xs[j] * qs);
      qf[sub][c] = h;
    }
  }

  f32x4 accO[2][2];   // [q-subtile][d8 within this wave's 32-dim D-quarter]
  #pragma unroll
  for (int sub = 0; sub < 2; ++sub)
    #pragma unroll
    for (int i = 0; i < 2; ++i) accO[sub][i] = (f32x4){0.f, 0.f, 0.f, 0.f};

  // staging decomposition (512 threads)
  const int krow = t >> 3, kcol = (t & 7) * 16;        // K: 64 rows x 128
  const int vp = t & 31, dseg = (t >> 5) * 8;          // V: 32 key-pairs x 8 d

  F32R16 kreg, vreg;

#define ISSUE_K(KT)                                                            \
  {                                                                            \
    const float4* gk4 = (const float4*)(K +                                    \
        ((size_t)(b * S_ + (KT) * TK + krow)) * D_ + kcol);                    \
    _Pragma("unroll") for (int i = 0; i < 4; ++i) kreg.q[i] = gk4[i];          \
  }
#define ISSUE_V(KT)                                                            \
  {                                                                            \
    const float4* gv4 = (const float4*)(V +                                    \
        ((size_t)(b * S_ + (KT) * TK + 2 * vp)) * D_ + dseg);                  \
    vreg.q[0] = gv4[0];                                                        \
    vreg.q[1] = gv4[1];                                                        \
    vreg.q[2] = gv4[32];  /* +128 floats = next key row */                     \
    vreg.q[3] = gv4[33];                                                       \
  }
#define CONV_K(KB)                                                             \
  {                                                                            \
    _Pragma("unroll") for (int g = 0; g < 2; ++g) {                            \
      f16x8 h;                                                                 \
      _Pragma("unroll") for (int j = 0; j < 8; ++j)                            \
        h[j] = (_Float16)kreg.f[g * 8 + j];                                    \
      *(f16x8*)&(KB)[krow * KSTR + kcol + g * 8] = h;                          \
    }                                                                          \
  }
#define CONV_V()                                                               \
  {                                                                            \
    _Pragma("unroll") for (int d = 0; d < 8; ++d) {                            \
      f16x2 h2 = {(_Float16)vreg.f[d], (_Float16)vreg.f[8 + d]};               \
      *(f16x2*)&sVT[(dseg + d) * VSTR + 2 * vp] = h2;                          \
    }                                                                          \
  }

  // ---- prologue: K(0) -> sK0 ----
  ISSUE_K(0)
  CONV_K(sK0)

  for (int kt = 0; kt < NT; ++kt) {
    __syncthreads();   // A: prev PV done (sVT/sP free); K(kt) visible

    ISSUE_V(kt);
    if (kt + 1 < NT) ISSUE_K(kt + 1)

    _Float16* const sKc = (kt & 1) ? sK1 : sK0;

    // ---- QK^T: 2 q-subtiles x 16 keys (this wave's phase) ----
    f32x4 s[2];
    {
      f32x4 a0 = (f32x4){0.f, 0.f, 0.f, 0.f};
      f32x4 a1 = (f32x4){0.f, 0.f, 0.f, 0.f};
      #pragma unroll
      for (int c = 0; c < 4; ++c) {
        const f16x8 bh = *(const f16x8*)&sKc[(kph * 16 + l15) * KSTR
                                             + c * 32 + quad * 8];
        a0 = __builtin_amdgcn_mfma_f32_16x16x32_f16(qf[0][c], bh, a0, 0, 0, 0);
        a1 = __builtin_amdgcn_mfma_f32_16x16x32_f16(qf[1][c], bh, a1, 0, 0, 0);
      }
      s[0] = a0;
      s[1] = a1;
    }

    // ---- local max -> LDS exchange (block-common m) ----
    #pragma unroll
    for (int sub = 0; sub < 2; ++sub)
      #pragma unroll
      for (int r = 0; r < 4; ++r) {
        const float mxl = row16_max(s[sub][r]);
        if (l15 == 0)
          sMx[kph * 64 + qg * 32 + sub * 16 + quad * 4 + r] = mxl;
      }

    // ---- convert staged tiles (waits vmcnt; QK above covered latency) ----
    CONV_V()
    if (kt + 1 < NT) { CONV_K(((kt & 1) ? sK0 : sK1)) }

    __syncthreads();   // B: mx + V(kt) + K(kt+1) visible

    // ---- block-common m, rescale, P = exp2(s-m), dropout, write P ----
    int changed = 0;
    float mn[2][4];
    #pragma unroll
    for (int sub = 0; sub < 2; ++sub)
      #pragma unroll
      for (int r = 0; r < 4; ++r) {
        const int row = qg * 32 + sub * 16 + quad * 4 + r;
        const float m4 = fmaxf(fmaxf(sMx[row], sMx[64 + row]),
                               fmaxf(sMx[128 + row], sMx[192 + row]));
        mn[sub][r] = fmaxf(m_[sub][r], m4);
        changed |= (mn[sub][r] > m_[sub][r]);
      }
    if (__ballot(changed) != 0ull) {
      #pragma unroll
      for (int sub = 0; sub < 2; ++sub)
        #pragma unroll
        for (int r = 0; r < 4; ++r) {
          const float alpha = __builtin_amdgcn_exp2f(m_[sub][r] - mn[sub][r]);
          m_[sub][r] = mn[sub][r];
          l_[sub][r] *= alpha;
          accO[sub][0][r] *= alpha;
          accO[sub][1][r] *= alpha;
        }
    }
    #pragma unroll
    for (int sub = 0; sub < 2; ++sub) {
      #pragma unroll
      for (int r = 0; r < 4; ++r) {
        const float p = __builtin_amdgcn_exp2f(s[sub][r] - m_[sub][r]);
        l_[sub][r] += row16_sum(p);
        const int row = qg * 32 + sub * 16 + quad * 4 + r;
        const uint32_t bits =
            jax_bits(jq[sub][r] + (uint32_t)(kt * TK + kph * 16) + (uint32_t)l15);
        sP[row * PSTR + kph * 16 + l15] = (_Float16)((bits < TH9) ? p : 0.0f);
      }
    }
    __syncthreads();   // C: P(kt) visible to all waves

    // ---- PV: O[32q x 32d-quarter] += P[32 x 64] * V[64 x 32dq] ----
    #pragma unroll
    for (int kseg = 0; kseg < 2; ++kseg) {
      const f16x8 ap0 = *(const f16x8*)&sP[(qg * 32 + l15) * PSTR
                                           + kseg * 32 + quad * 8];
      const f16x8 ap1 = *(const f16x8*)&sP[(qg * 32 + 16 + l15) * PSTR
                                           + kseg * 32 + quad * 8];
      #pragma unroll
      for (int dq = 0; dq < 2; ++dq) {
        const int d8 = kph * 2 + dq;
        const f16x8 bv = *(const f16x8*)&sVT[(d8 * 16 + l15) * VSTR
                                             + kseg * 32 + quad * 8];
        accO[0][dq] = __builtin_amdgcn_mfma_f32_16x16x32_f16(ap0, bv, accO[0][dq], 0, 0, 0);
        accO[1][dq] = __builtin_amdgcn_mfma_f32_16x16x32_f16(ap1, bv, accO[1][dq], 0, 0, 0);
      }
    }
  }
#undef ISSUE_K
#undef ISSUE_V
#undef CONV_K
#undef CONV_V

  // ---- epilogue: l = sum of 4 phase partials; disjoint O stores ----
  __syncthreads();
  #pragma unroll
  for (int sub = 0; sub < 2; ++sub)
    #pragma unroll
    for (int r = 0; r < 4; ++r)
      if (l15 == 0)
        sMx[kph * 64 + qg * 32 + sub * 16 + quad * 4 + r] = l_[sub][r];
  __syncthreads();
  #pragma unroll
  for (int sub = 0; sub < 2; ++sub) {
    #pragma unroll
    for (int r = 0; r < 4; ++r) {
      const int row = qg * 32 + sub * 16 + quad * 4 + r;
      const float lt = sMx[row] + sMx[64 + row] + sMx[128 + row] + sMx[192 + row];
      const float inv = 1.0f / (lt * kp);
      float* op = OUT + ((size_t)(b * S_ + blockIdx.x * TQ + row)) * D_;
      op[(kph * 2 + 0) * 16 + l15] = accO[sub][0][r] * inv;
      op[(kph * 2 + 1) * 16 + l15] = accO[sub][1][r] * inv;
    }
  }
}

extern "C" void kernel_launch(void* const* d_in, const int* in_sizes, int n_in,
                              void* d_out, int out_size, void* d_ws, size_t ws_size,
                              hipStream_t stream) {
  const float* q   = (const float*)d_in[0];
  const float* k   = (const float*)d_in[1];
  const float* v   = (const float*)d_in[2];
  const float* isf = (const float*)d_in[3];
  const float* dp  = (const float*)d_in[4];
  float* out = (float*)d_out;

  dim3 grid(S_ / TQ, B_);
  attn_mfma_kernel<<<grid, dim3(512), 63488, stream>>>(q, k, v, isf, dp, out);
}

// Round 13
// 307.525 us; speedup vs baseline: 1.3633x; 1.3633x over previous
//
#include <hip/hip_runtime.h>
#include <stdint.h>

// B=16, S=2048, D=128 attention, per-query scale folded into Q (with log2e),
// online softmax in exp2 domain, exact JAX partitionable-threefry dropout
// (key 42, p=0.1), @V.
// Round 13: r8's proven fat-wave shape (32 q-rows x 32 keys per wave, 2
// subtiles sharing every K/V fragment read) split into 512 blocks x 256
// threads (TQ=64): 2 blocks/CU at 46 KB LDS (r6-proven co-residency) so the
// two blocks' barriers DEcorrelate — one block issues while the other
// drains.  Single-buffered K/V (2 barriers/iter), register prefetch of the
// next tile, per-wave private P/softmax, 2-phase merge via LDS overlay.

#define B_ 16
#define S_ 2048
#define D_ 128
#define TQ 64     // q rows per block (2 groups x 32)
#define TK 64     // keys per iteration (each kph-wave consumes 32)
#define NT (S_ / TK)
#define KSTR 136  // f16 stride for K rows (128+8): 272B, 16B-aligned
#define VSTR 72   // f16 stride for V^T rows (64+8): 144B
#define PSTR 40   // f16 stride for per-wave P rows (32+8): 80B

typedef float f32x4 __attribute__((ext_vector_type(4)));
typedef _Float16 f16x8 __attribute__((ext_vector_type(8)));
typedef _Float16 f16x2 __attribute__((ext_vector_type(2)));

union F32R32 { float4 q[8]; float f[32]; };
union F16R16 { float4 q[4]; float f[16]; };

// DPP row_ror reductions over 16-lane row groups.
#define DPP_ROR(x, ctrl) \
  __int_as_float(__builtin_amdgcn_update_dpp(0, __float_as_int(x), (ctrl), 0xf, 0xf, true))
__device__ __forceinline__ float row16_max(float x) {
  x = fmaxf(x, DPP_ROR(x, 0x128));
  x = fmaxf(x, DPP_ROR(x, 0x124));
  x = fmaxf(x, DPP_ROR(x, 0x122));
  x = fmaxf(x, DPP_ROR(x, 0x121));
  return x;
}
__device__ __forceinline__ float row16_sum(float x) {
  x += DPP_ROR(x, 0x128);
  x += DPP_ROR(x, 0x124);
  x += DPP_ROR(x, 0x122);
  x += DPP_ROR(x, 0x121);
  return x;
}

// threefry2x32, 20 rounds, key = (0, 42)  [jax.random.key(42)]
__device__ __forceinline__ uint2 threefry2x32_0_42(uint32_t x0, uint32_t x1) {
  const uint32_t k0 = 0u, k1 = 42u;
  const uint32_t k2 = 0x1BD11BDAu ^ k0 ^ k1;
  x0 += k0; x1 += k1;
#define TFR(r) { x0 += x1; x1 = __builtin_rotateleft32(x1, r); x1 ^= x0; }
  TFR(13) TFR(15) TFR(26) TFR(6)
  x0 += k1; x1 += k2 + 1u;
  TFR(17) TFR(29) TFR(16) TFR(24)
  x0 += k2; x1 += k0 + 2u;
  TFR(13) TFR(15) TFR(26) TFR(6)
  x0 += k0; x1 += k1 + 3u;
  TFR(17) TFR(29) TFR(16) TFR(24)
  x0 += k1; x1 += k2 + 4u;
  TFR(13) TFR(15) TFR(26) TFR(6)
  x0 += k2; x1 += k0 + 5u;
#undef TFR
  return make_uint2(x0, x1);
}

// HW-verified (round 2): partitionable path, counter (0, j), xor-fold.
__device__ __forceinline__ uint32_t jax_bits(uint32_t j) {
  const uint2 tf = threefry2x32_0_42(0u, j);
  return tf.x ^ tf.y;
}

__global__ __launch_bounds__(256, 2)
void attn_mfma_kernel(const float* __restrict__ Q, const float* __restrict__ K,
                      const float* __restrict__ V, const float* __restrict__ ISF,
                      const float* __restrict__ DP, float* __restrict__ OUT) {
  extern __shared__ __align__(16) char smem[];
  _Float16* const sK  = (_Float16*)smem;                // 64x136 f16 = 17408 B
  _Float16* const sVT = (_Float16*)(smem + 17408);      // 128x72 f16 = 18432 B
  _Float16* const sP  = (_Float16*)(smem + 35840);      // 4 x 32x40 = 10240 B
  // merge overlay (after final barrier):
  float* const sO1 = (float*)smem;                      // 64x128 f32 = 32768 B
  float* const sM1 = (float*)(smem + 32768);            // 64 f32
  float* const sL1 = (float*)(smem + 33024);            // 64 f32

  const int t    = threadIdx.x;
  const int lane = t & 63;
  const int l15  = lane & 15;
  const int quad = lane >> 4;
  const int w    = t >> 6;       // 0..3
  const int qg   = w & 1;        // q-group: 32 rows
  const int kph  = w >> 1;       // key phase: 0 = keys [0,32), 1 = [32,64)
  const int b    = blockIdx.y;
  const int qb   = blockIdx.x * TQ + qg * 32;

  const float kp = 1.0f - DP[0];
  const uint32_t TH9 = (__float_as_uint(1.0f + kp) & 0x7FFFFFu) << 9;

  float m_[2][4], l_[2][4];
  uint32_t jq[2][4];
  #pragma unroll
  for (int sub = 0; sub < 2; ++sub)
    #pragma unroll
    for (int r = 0; r < 4; ++r) {
      m_[sub][r] = -INFINITY;
      l_[sub][r] = 0.0f;
      jq[sub][r] = ((uint32_t)b << 22)
                 + (uint32_t)(qb + sub * 16 + quad * 4 + r) * (uint32_t)S_;
    }

  // ---- Q fragments (2 subtiles), f16, 1/isf and log2(e) folded in ----
  f16x8 qf[2][4];
  #pragma unroll
  for (int sub = 0; sub < 2; ++sub) {
    const int qrow = qb + sub * 16 + l15;
    const float qs = 1.4426950408889634f / ISF[b * S_ + qrow];
    const float* qp = Q + ((size_t)(b * S_ + qrow)) * D_;
    #pragma unroll
    for (int c = 0; c < 4; ++c) {
      const float4 a  = *(const float4*)(qp + c * 32 + quad * 8);
      const float4 d2 = *(const float4*)(qp + c * 32 + quad * 8 + 4);
      const float xs[8] = {a.x, a.y, a.z, a.w, d2.x, d2.y, d2.z, d2.w};
      f16x8 h;
      #pragma unroll
      for (int j = 0; j < 8; ++j) h[j] = (_Float16)(xs[j] * qs);
      qf[sub][c] = h;
    }
  }

  f32x4 accO[2][8];
  #pragma unroll
  for (int sub = 0; sub < 2; ++sub)
    #pragma unroll
    for (int i = 0; i < 8; ++i) accO[sub][i] = (f32x4){0.f, 0.f, 0.f, 0.f};

  _Float16* const pwv = &sP[w * 32 * PSTR];

  // staging decomposition (256 threads)
  const int krow = t >> 2, kcol = (t & 3) * 32;        // K: 64 rows x 128
  const int vp = t & 31, dseg = (t >> 5) * 16;         // V: 32 key-pairs x 16 d

  F32R32 kreg;          // prefetched K floats (32/thread)
  F16R16 vreg0, vreg1;  // prefetched V floats (16+16/thread)

#define ISSUE_LOADS(KT)                                                        \
  {                                                                            \
    const float4* gk4 = (const float4*)(K +                                    \
        ((size_t)(b * S_ + (KT) * TK + krow)) * D_ + kcol);                    \
    _Pragma("unroll") for (int i = 0; i < 8; ++i) kreg.q[i] = gk4[i];          \
    const float4* gv4 = (const float4*)(V +                                    \
        ((size_t)(b * S_ + (KT) * TK + 2 * vp)) * D_ + dseg);                  \
    _Pragma("unroll") for (int i = 0; i < 4; ++i) {                            \
      vreg0.q[i] = gv4[i];                                                     \
      vreg1.q[i] = gv4[i + 32];  /* +128 floats = next key row */              \
    }                                                                          \
  }

#define CONVERT_TILES()                                                        \
  {                                                                            \
    _Pragma("unroll") for (int g = 0; g < 4; ++g) {                            \
      f16x8 h;                                                                 \
      _Pragma("unroll") for (int j = 0; j < 8; ++j)                            \
        h[j] = (_Float16)kreg.f[g * 8 + j];                                    \
      *(f16x8*)&sK[krow * KSTR + kcol + g * 8] = h;                            \
    }                                                                          \
    _Pragma("unroll") for (int d = 0; d < 16; ++d) {                           \
      f16x2 h2 = {(_Float16)vreg0.f[d], (_Float16)vreg1.f[d]};                 \
      *(f16x2*)&sVT[(dseg + d) * VSTR + 2 * vp] = h2;                          \
    }                                                                          \
  }

  // ---- prologue: tile 0 -> LDS; issue loads for tile 1 ----
  ISSUE_LOADS(0)
  CONVERT_TILES()
  ISSUE_LOADS(1)
  __syncthreads();   // tile 0 visible

  for (int kt = 0; kt < NT; ++kt) {
    // ---- QK^T: 2 q-subtiles x 32 keys; K-frags shared across subtiles ----
    f32x4 s[2][2];
    #pragma unroll
    for (int n = 0; n < 2; ++n) {
      f32x4 a0 = (f32x4){0.f, 0.f, 0.f, 0.f};
      f32x4 a1 = (f32x4){0.f, 0.f, 0.f, 0.f};
      #pragma unroll
      for (int c = 0; c < 4; ++c) {
        const f16x8 bh = *(const f16x8*)&sK[(kph * 32 + n * 16 + l15) * KSTR
                                            + c * 32 + quad * 8];
        a0 = __builtin_amdgcn_mfma_f32_16x16x32_f16(qf[0][c], bh, a0, 0, 0, 0);
        a1 = __builtin_amdgcn_mfma_f32_16x16x32_f16(qf[1][c], bh, a1, 0, 0, 0);
      }
      s[0][n] = a0;
      s[1][n] = a1;
    }

    // ---- dropout bits (independent of scores; fills the MFMA shadow) ----
    uint32_t rb[2][2][4];
    #pragma unroll
    for (int sub = 0; sub < 2; ++sub)
      #pragma unroll
      for (int n = 0; n < 2; ++n) {
        const uint32_t jcol = (uint32_t)(kt * TK + kph * 32 + n * 16 + l15);
        #pragma unroll
        for (int r = 0; r < 4; ++r)
          rb[sub][n][r] = jax_bits(jq[sub][r] + jcol);
      }

    // ---- online softmax (exp2 domain), per subtile ----
    float mx[2][4];
    int changed = 0;
    #pragma unroll
    for (int sub = 0; sub < 2; ++sub)
      #pragma unroll
      for (int r = 0; r < 4; ++r) {
        mx[sub][r] = row16_max(fmaxf(s[sub][0][r], s[sub][1][r]));
        changed |= (mx[sub][r] > m_[sub][r]);
      }
    if (__ballot(changed) != 0ull) {
      #pragma unroll
      for (int sub = 0; sub < 2; ++sub)
        #pragma unroll
        for (int r = 0; r < 4; ++r) {
          const float mnew = fmaxf(m_[sub][r], mx[sub][r]);
          const float alpha = __builtin_amdgcn_exp2f(m_[sub][r] - mnew);
          m_[sub][r] = mnew;
          l_[sub][r] *= alpha;
          #pragma unroll
          for (int i = 0; i < 8; ++i) accO[sub][i][r] *= alpha;
        }
    }
    #pragma unroll
    for (int sub = 0; sub < 2; ++sub)
      #pragma unroll
      for (int r = 0; r < 4; ++r) {
        const float p0 = __builtin_amdgcn_exp2f(s[sub][0][r] - m_[sub][r]);
        const float p1 = __builtin_amdgcn_exp2f(s[sub][1][r] - m_[sub][r]);
        s[sub][0][r] = p0;
        s[sub][1][r] = p1;
        l_[sub][r] += row16_sum(p0 + p1);
      }

    // ---- masked f16 P into wave-private LDS ----
    #pragma unroll
    for (int sub = 0; sub < 2; ++sub)
      #pragma unroll
      for (int n = 0; n < 2; ++n) {
        const int col = n * 16 + l15;
        #pragma unroll
        for (int r = 0; r < 4; ++r) {
          const float pf = (rb[sub][n][r] < TH9) ? s[sub][n][r] : 0.0f;
          pwv[(sub * 16 + quad * 4 + r) * PSTR + col] = (_Float16)pf;
        }
      }
    __threadfence_block();   // order cross-lane P writes before A-frag reads

    // ---- PV: per subtile O[16x128] += P[16x32] * V[32x128]; V shared ----
    {
      const f16x8 ap0 = *(const f16x8*)&pwv[l15 * PSTR + quad * 8];
      const f16x8 ap1 = *(const f16x8*)&pwv[(16 + l15) * PSTR + quad * 8];
      #pragma unroll
      for (int d8 = 0; d8 < 8; ++d8) {
        const f16x8 bv = *(const f16x8*)&sVT[(d8 * 16 + l15) * VSTR
                                             + kph * 32 + quad * 8];
        accO[0][d8] = __builtin_amdgcn_mfma_f32_16x16x32_f16(ap0, bv, accO[0][d8], 0, 0, 0);
        accO[1][d8] = __builtin_amdgcn_mfma_f32_16x16x32_f16(ap1, bv, accO[1][d8], 0, 0, 0);
      }
    }

    // ---- pipeline advance: convert kt+1 (regs already loaded); load kt+2 ----
    if (kt + 1 < NT) {
      __syncthreads();        // A: all waves done reading tile kt
      CONVERT_TILES()
      if (kt + 2 < NT) ISSUE_LOADS(kt + 2)
      __syncthreads();        // B: tile kt+1 visible
    }
  }
#undef ISSUE_LOADS
#undef CONVERT_TILES

  // ---- merge the two key-phase waves of each q-group ----
  __syncthreads();   // loop LDS dead; overlay live
  if (kph == 1) {
    #pragma unroll
    for (int sub = 0; sub < 2; ++sub) {
      if (l15 == 0) {
        #pragma unroll
        for (int r = 0; r < 4; ++r) {
          const int gr = qg * 32 + sub * 16 + quad * 4 + r;
          sM1[gr] = m_[sub][r];
          sL1[gr] = l_[sub][r];
        }
      }
      #pragma unroll
      for (int d8 = 0; d8 < 8; ++d8)
        #pragma unroll
        for (int r = 0; r < 4; ++r) {
          const int gr = qg * 32 + sub * 16 + quad * 4 + r;
          sO1[gr * D_ + d8 * 16 + l15] = accO[sub][d8][r];
        }
    }
  }
  __syncthreads();
  if (kph == 0) {
    #pragma unroll
    for (int sub = 0; sub < 2; ++sub) {
      float a0s[4], a1s[4];
      #pragma unroll
      for (int r = 0; r < 4; ++r) {
        const int gr = qg * 32 + sub * 16 + quad * 4 + r;
        const float m1  = sM1[gr];
        const float l1v = sL1[gr];
        const float mf = fmaxf(m_[sub][r], m1);
        const float a0 = __builtin_amdgcn_exp2f(m_[sub][r] - mf);
        const float a1 = __builtin_amdgcn_exp2f(m1 - mf);
        const float inv = 1.0f / ((a0 * l_[sub][r] + a1 * l1v) * kp);
        a0s[r] = a0 * inv;
        a1s[r] = a1 * inv;
      }
      #pragma unroll
      for (int d8 = 0; d8 < 8; ++d8)
        #pragma unroll
        for (int r = 0; r < 4; ++r) {
          const int gr = qg * 32 + sub * 16 + quad * 4 + r;
          const float o1 = sO1[gr * D_ + d8 * 16 + l15];
          OUT[((size_t)(b * S_ + blockIdx.x * TQ + gr)) * D_ + d8 * 16 + l15] =
              accO[sub][d8][r] * a0s[r] + o1 * a1s[r];
        }
    }
  }
}

extern "C" void kernel_launch(void* const* d_in, const int* in_sizes, int n_in,
                              void* d_out, int out_size, void* d_ws, size_t ws_size,
                              hipStream_t stream) {
  const float* q   = (const float*)d_in[0];
  const float* k   = (const float*)d_in[1];
  const float* v   = (const float*)d_in[2];
  const float* isf = (const float*)d_in[3];
  const float* dp  = (const float*)d_in[4];
  float* out = (float*)d_out;

  dim3 grid(S_ / TQ, B_);
  attn_mfma_kernel<<<grid, dim3(256), 46080, stream>>>(q, k, v, isf, dp, out);
}